// Round 1
// baseline (644.671 us; speedup 1.0000x reference)
//
#include <hip/hip_runtime.h>
#include <stdint.h>

#define NN 8192      // nodes
#define D0 128
#define D1 256
#define D2 256
#define QH 128
#define EPSV 1e-5f

using bf16x8 = __attribute__((ext_vector_type(8))) __bf16;
using f32x4  = __attribute__((ext_vector_type(4))) float;

__device__ __forceinline__ unsigned short f2bf(float f) {
    union { float f; unsigned int u; } v; v.f = f;
    unsigned int r = v.u + 0x7FFFu + ((v.u >> 16) & 1u);   // RNE
    return (unsigned short)(r >> 16);
}
__device__ __forceinline__ float bf2f(unsigned short h) {
    union { unsigned int u; float f; } v; v.u = ((unsigned int)h) << 16;
    return v.f;
}
// pack two fp32 -> one u32 of two bf16 (RNE), low = first arg
__device__ __forceinline__ unsigned pkbf(float a, float b) {
    unsigned r;
    asm("v_cvt_pk_bf16_f32 %0, %1, %2" : "=v"(r) : "v"(a), "v"(b));
    return r;
}
// async global->LDS, 16B per lane; lds dest is wave-uniform base (HW: base + lane*16)
__device__ __forceinline__ void async_ld16(const void* g, void* l) {
    __builtin_amdgcn_global_load_lds(
        (__attribute__((address_space(1))) void*)(g),
        (__attribute__((address_space(3))) void*)(l), 16, 0, 0);
}

// ---------------- batchnorm partial stats + zero the fp32 accumulators ----------------
__global__ void k_stats(const float* __restrict__ state,
                        float* __restrict__ psum, float* __restrict__ psq,
                        float* __restrict__ acc4k, float* __restrict__ rsA) {
    int j = threadIdx.x;            // 0..127 = feature
    int b = blockIdx.x;             // 0..255, 32 rows each
    int gid = b * 128 + j;
    if (gid < 8192) rsA[gid] = 0.f;          // row-sum accumulator (gemm1 atomics)
    if (gid < 1024) acc4k[gid] = 0.f;        // colA,colB,colH1,s2 (contiguous 4KB)
    const float* p = state + (size_t)b * 32 * D0 + j;
    float s = 0.f, sq = 0.f;
#pragma unroll 4
    for (int r = 0; r < 32; ++r) { float x = p[(size_t)r * D0]; s += x; sq += x * x; }
    psum[b * D0 + j] = s;
    psq [b * D0 + j] = sq;
}

// ---------------- finalize scale/shift + c1 ----------------
__global__ void k_finalize(const float* __restrict__ psum, const float* __restrict__ psq,
                           const float* __restrict__ gamma, const float* __restrict__ beta,
                           const float* __restrict__ W1,
                           float* __restrict__ scale, float* __restrict__ shift,
                           float* __restrict__ c1) {
    __shared__ float s_shift[D0];
    int t = threadIdx.x;            // 256 threads
    if (t < D0) {
        float s = 0.f, sq = 0.f;
        for (int b = 0; b < 256; ++b) { s += psum[b * D0 + t]; sq += psq[b * D0 + t]; }
        float mean = s * (1.0f / NN);
        float var  = sq * (1.0f / NN) - mean * mean;
        float sc = gamma[t] * rsqrtf(var + EPSV);
        float sh = beta[t] - mean * sc;
        scale[t] = sc; shift[t] = sh; s_shift[t] = sh;
    }
    __syncthreads();
    float acc = 0.f;
    for (int k = 0; k < D0; ++k) acc += s_shift[k] * W1[(size_t)k * D1 + t];
    c1[t] = acc;
}

// ---------------- weights -> bf16, transposed [n][k], W1 scaled ----------------
__global__ void k_prep_weights(const float* __restrict__ W1, const float* __restrict__ W2,
                               const float* __restrict__ scale,
                               unsigned short* __restrict__ W1st,  // [256][128]
                               unsigned short* __restrict__ W2t) { // [256][256]
    int idx = blockIdx.x * 256 + threadIdx.x;
    if (idx < 32768) {
        int n = idx >> 7, k = idx & 127;
        W1st[idx] = f2bf(W1[(size_t)k * D1 + n] * scale[k]);
    } else {
        int i = idx - 32768; int n = i >> 8, k = i & 255;
        W2t[i] = f2bf(W2[(size_t)k * D2 + n]);
    }
}

// ---------------- small MFMA GEMM: out[m][n] = A[m][k] @ Bt[n][k]^T (+ bias) ----------------
template <int N, int K, bool A_FP32, bool BIAS>
__global__ __launch_bounds__(256, 4) void k_small_gemm(
        const void* __restrict__ Aptr, const unsigned short* __restrict__ Bt,
        const float* __restrict__ bias, unsigned short* __restrict__ out) {
    constexpr int WN = N / 4;
    constexpr int NJ = WN / 16;
    constexpr int BI = N / 64;
    __shared__ unsigned short Alds[32 * 32];
    __shared__ unsigned short Blds[N * 32];
    int t = threadIdx.x, lane = t & 63, w = t >> 6;
    int m0 = blockIdx.x * 32;
    int lr = lane & 15, lk = (lane >> 4) * 8;
    int wc = w * WN;
    f32x4 acc[2][NJ] = {};

    for (int kk = 0; kk < K; kk += 32) {
        __syncthreads();
        if constexpr (A_FP32) {
            const float* A = (const float*)Aptr;
            int row = t >> 3, kc = (t & 7) * 4;
            float4 v = *(const float4*)(A + (size_t)(m0 + row) * K + kk + kc);
            uint2 p;
            p.x = ((unsigned)f2bf(v.y) << 16) | f2bf(v.x);
            p.y = ((unsigned)f2bf(v.w) << 16) | f2bf(v.z);
            *(uint2*)&Alds[row * 32 + kc] = p;
        } else {
            if (w < 2) {
                const unsigned short* A = (const unsigned short*)Aptr;
                int row = w * 16 + (lane >> 2);
                async_ld16(A + (size_t)(m0 + row) * K + kk + (lane & 3) * 8, &Alds[w * 512]);
            }
        }
#pragma unroll
        for (int i = 0; i < BI; ++i) {
            int n = w * WN + i * 16 + (lane >> 2);
            async_ld16(Bt + (size_t)n * K + kk + (lane & 3) * 8, &Blds[(w * WN + i * 16) * 32]);
        }
        __syncthreads();
        bf16x8 a[2], b[NJ];
#pragma unroll
        for (int i = 0; i < 2; ++i) a[i] = *(const bf16x8*)&Alds[(i * 16 + lr) * 32 + lk];
#pragma unroll
        for (int j = 0; j < NJ; ++j) b[j] = *(const bf16x8*)&Blds[(wc + j * 16 + lr) * 32 + lk];
#pragma unroll
        for (int i = 0; i < 2; ++i)
#pragma unroll
            for (int j = 0; j < NJ; ++j)
                acc[i][j] = __builtin_amdgcn_mfma_f32_16x16x32_bf16(a[i], b[j], acc[i][j], 0, 0, 0);
    }
    int q = lane >> 4;
#pragma unroll
    for (int j = 0; j < NJ; ++j) {
        int n = wc + j * 16 + lr;
        float bv = 0.f;
        if constexpr (BIAS) bv = bias[n];
#pragma unroll
        for (int i = 0; i < 2; ++i) {
#pragma unroll
            for (int r = 0; r < 4; ++r) {
                int m = m0 + i * 16 + q * 4 + r;
                out[(size_t)m * N + n] = f2bf(acc[i][j][r] + bv);
            }
        }
    }
}

// ---------------- transpose [8192][256] bf16 -> [256][8192] bf16, + fp32 colsum ----------------
__global__ void k_transpose(const unsigned short* __restrict__ in, unsigned short* __restrict__ out,
                            float* __restrict__ colsum) {
    __shared__ unsigned short tile[64 * 68];
    __shared__ float cp[4][64];
    int t = threadIdx.x;
    int r0 = blockIdx.x * 64, c0 = blockIdx.y * 64;
#pragma unroll
    for (int p = 0; p < 4; ++p) {
        int row = (t >> 4) + p * 16, col = (t & 15) * 4;
        *(ushort4*)&tile[row * 68 + col] = *(const ushort4*)&in[(size_t)(r0 + row) * 256 + c0 + col];
    }
    __syncthreads();
    int n = t >> 2;
#pragma unroll
    for (int s = 0; s < 2; ++s) {
        int mo = (t & 3) * 16 + s * 8;
        unsigned short v[8];
#pragma unroll
        for (int e = 0; e < 8; ++e) v[e] = tile[(mo + e) * 68 + n];
        *(uint4*)&out[(size_t)(c0 + n) * NN + r0 + mo] = *(const uint4*)v;
    }
    int col = t & 63, gg = t >> 6;
    float s = 0.f;
#pragma unroll
    for (int r = 0; r < 16; ++r) s += bf2f(tile[(gg * 16 + r) * 68 + col]);
    cp[gg][col] = s;
    __syncthreads();
    if (t < 64) atomicAdd(colsum + c0 + t, cp[0][t] + cp[1][t] + cp[2][t] + cp[3][t]);
}

// ---------------- big GEMM, fp32 A fused-cast: Cp += f32A(cast bf16) @ Yt^T -------------
// BM=128, BN=256, BK=32, split-K=8. grid(64,8), 256 thr = 4 waves of 64x128 tiles.
// A: reg-staged (float4 x4 -> cvt_pk -> swizzled ds_write_b128); rowsum fused (RSUM).
// B: pre-swizzled-source global_load_lds (16B). Double-buffered LDS, 1 barrier/K-step.
// Swizzle: 16B chunk c of row r stored at chunk c ^ xs(r), xs(r) = (r ^ (r>>2)) & 3.
template <bool RSUM>
__global__ __launch_bounds__(256, 2) void k_big_gemm3(
        const float* __restrict__ A, const unsigned short* __restrict__ Yt,
        float* __restrict__ Cp, float* __restrict__ rsA) {
    __shared__ unsigned short Alds[2][128 * 32];   // 8KB  x2
    __shared__ unsigned short Blds[2][256 * 32];   // 16KB x2 -> 48KB total
    int t = threadIdx.x, lane = t & 63, w = t >> 6;
    int m0 = blockIdx.x * 128;
    int kbeg = blockIdx.y * 1024;
    int wr = (w & 1) * 64, wc = (w >> 1) * 128;
    int lr = lane & 15, q = lane >> 4;
    f32x4 acc[4][8] = {};

    // A staging: lane covers (row = t>>1, 16 k-elems = 2 chunks)
    int arow = t >> 1;
    int axs = (arow ^ (arow >> 2)) & 3;
    int ac0 = (t & 1) * 2;
    const float* agp = A + (size_t)(m0 + arow) * NN + kbeg + (t & 1) * 16;
    int aw0 = arow * 32 + ((ac0 ^ axs) & 3) * 8;
    int aw1 = arow * 32 + (((ac0 + 1) ^ axs) & 3) * 8;

    // B staging: wave w covers rows [w*64, w*64+64), 4 calls of 16 rows
    int bxs = ((lane >> 2) ^ (lane >> 4)) & 3;
    int bchunk = (lane & 3) ^ bxs;
    const unsigned short* bgp = Yt + (size_t)(w * 64 + (lane >> 2)) * NN + kbeg + bchunk * 8;

    // read-side swizzle (shorts)
    int xsr = (lr ^ (lr >> 2)) & 3;
    int lks = ((q ^ xsr) & 3) * 8;

    float rs = 0.f;
    float4 av0, av1, av2, av3;

    // ---- prologue: stage tile 0 into buf 0
    av0 = *(const float4*)(agp + 0);
    av1 = *(const float4*)(agp + 4);
    av2 = *(const float4*)(agp + 8);
    av3 = *(const float4*)(agp + 12);
#pragma unroll
    for (int c = 0; c < 4; ++c)
        async_ld16(bgp + (size_t)c * 16 * NN, &Blds[0][(w * 64 + c * 16) * 32]);
    {
        uint4 u0 = { pkbf(av0.x, av0.y), pkbf(av0.z, av0.w), pkbf(av1.x, av1.y), pkbf(av1.z, av1.w) };
        uint4 u1 = { pkbf(av2.x, av2.y), pkbf(av2.z, av2.w), pkbf(av3.x, av3.y), pkbf(av3.z, av3.w) };
        *(uint4*)&Alds[0][aw0] = u0;
        *(uint4*)&Alds[0][aw1] = u1;
    }
    if constexpr (RSUM)
        rs += av0.x + av0.y + av0.z + av0.w + av1.x + av1.y + av1.z + av1.w
            + av2.x + av2.y + av2.z + av2.w + av3.x + av3.y + av3.z + av3.w;
    __syncthreads();

#pragma unroll 2
    for (int it = 0; it < 32; ++it) {
        int p = it & 1;
        bool more = (it < 31);
        if (more) {
            int ko = (it + 1) * 32;
            av0 = *(const float4*)(agp + ko + 0);     // in flight during MFMA below
            av1 = *(const float4*)(agp + ko + 4);
            av2 = *(const float4*)(agp + ko + 8);
            av3 = *(const float4*)(agp + ko + 12);
#pragma unroll
            for (int c = 0; c < 4; ++c)
                async_ld16(bgp + ko + (size_t)c * 16 * NN, &Blds[p ^ 1][(w * 64 + c * 16) * 32]);
        }
        bf16x8 a[4], b[8];
#pragma unroll
        for (int i = 0; i < 4; ++i) a[i] = *(const bf16x8*)&Alds[p][(wr + i * 16 + lr) * 32 + lks];
#pragma unroll
        for (int j = 0; j < 8; ++j) b[j] = *(const bf16x8*)&Blds[p][(wc + j * 16 + lr) * 32 + lks];
#pragma unroll
        for (int i = 0; i < 4; ++i)
#pragma unroll
            for (int j = 0; j < 8; ++j)
                acc[i][j] = __builtin_amdgcn_mfma_f32_16x16x32_bf16(a[i], b[j], acc[i][j], 0, 0, 0);
        if (more) {
            uint4 u0 = { pkbf(av0.x, av0.y), pkbf(av0.z, av0.w), pkbf(av1.x, av1.y), pkbf(av1.z, av1.w) };
            uint4 u1 = { pkbf(av2.x, av2.y), pkbf(av2.z, av2.w), pkbf(av3.x, av3.y), pkbf(av3.z, av3.w) };
            *(uint4*)&Alds[p ^ 1][aw0] = u0;
            *(uint4*)&Alds[p ^ 1][aw1] = u1;
            if constexpr (RSUM)
                rs += av0.x + av0.y + av0.z + av0.w + av1.x + av1.y + av1.z + av1.w
                    + av2.x + av2.y + av2.z + av2.w + av3.x + av3.y + av3.z + av3.w;
        }
        __syncthreads();
    }

    float* outp = Cp + (size_t)blockIdx.y * NN * 256;
#pragma unroll
    for (int i = 0; i < 4; ++i)
#pragma unroll
        for (int j = 0; j < 8; ++j) {
            int n = wc + j * 16 + lr;
#pragma unroll
            for (int r = 0; r < 4; ++r) {
                int m = m0 + wr + i * 16 + q * 4 + r;
                outp[(size_t)m * 256 + n] = acc[i][j][r];
            }
        }
    if constexpr (RSUM) {
        rs += __shfl_xor(rs, 1, 64);
        if ((lane & 1) == 0) atomicAdd(rsA + m0 + w * 32 + (lane >> 1), rs);
    }
}

// ---------------- s2[n] = colB[n] - sum_k colH1[k]*W2[k][n] ----------------
__global__ void k_s2(const float* __restrict__ colB, const float* __restrict__ colH1,
                     const float* __restrict__ W2, float* __restrict__ s2) {
    int n = threadIdx.x;
    float acc = 0.f;
    for (int k = 0; k < 256; ++k) acc += colH1[k] * W2[(size_t)k * 256 + n];
    s2[n] = colB[n] - acc;
}

// ---------------- reduce 8 split-K partials + bias + colsum-corr + relu -> bf16 H1 ----------
__global__ __launch_bounds__(256) void k_reduce8(
        const float* __restrict__ Cp, const float* __restrict__ rsA,
        const float* __restrict__ bias, const float* __restrict__ sn,
        unsigned short* __restrict__ out, float* __restrict__ colH1) {
    __shared__ float rs_s[16];
    __shared__ float cs[4][256];
    int t = threadIdx.x;
    int m0 = blockIdx.x * 16;
    const size_t S = (size_t)NN * 256;
    if (t < 16) rs_s[t] = rsA[m0 + t] * (1.0f / 8192.0f);
    __syncthreads();
    int g = t >> 6, cq = (t & 63) * 4;
    float4 snv = *(const float4*)(sn + cq);
    float4 bv  = *(const float4*)(bias + cq);
    float c0 = 0.f, c1a = 0.f, c2 = 0.f, c3 = 0.f;
#pragma unroll
    for (int r4 = 0; r4 < 4; ++r4) {
        int row = g * 4 + r4;
        size_t base = (size_t)(m0 + row) * 256 + cq;
        float4 a = {0.f, 0.f, 0.f, 0.f};
#pragma unroll
        for (int s = 0; s < 8; ++s) {
            float4 p = *(const float4*)(Cp + (size_t)s * S + base);
            a.x += p.x; a.y += p.y; a.z += p.z; a.w += p.w;
        }
        float rsv = rs_s[row];
        float x0 = fmaxf(a.x + bv.x - rsv * snv.x, 0.f);
        float x1 = fmaxf(a.y + bv.y - rsv * snv.y, 0.f);
        float x2 = fmaxf(a.z + bv.z - rsv * snv.z, 0.f);
        float x3 = fmaxf(a.w + bv.w - rsv * snv.w, 0.f);
        ushort4 o; o.x = f2bf(x0); o.y = f2bf(x1); o.z = f2bf(x2); o.w = f2bf(x3);
        *(ushort4*)(out + base) = o;
        c0 += x0; c1a += x1; c2 += x2; c3 += x3;
    }
    cs[g][cq] = c0; cs[g][cq + 1] = c1a; cs[g][cq + 2] = c2; cs[g][cq + 3] = c3;
    __syncthreads();
    float tot = cs[0][t] + cs[1][t] + cs[2][t] + cs[3][t];
    atomicAdd(colH1 + t, tot);
}

// ---------------- fused: reduce 8 partials -> H2(fp32, LDS only) -> Q-head -> out -------
__global__ __launch_bounds__(256) void k_reduce_qhead(
        const float* __restrict__ Cp, const float* __restrict__ rsA,
        const float* __restrict__ bias, const float* __restrict__ sn,
        const float* __restrict__ Wq1, const float* __restrict__ bq1,
        const float* __restrict__ Wq2, const float* __restrict__ bq2,
        float* __restrict__ out) {
    __shared__ float sh[16][256];   // 16KB
    __shared__ float rs_s[16];
    __shared__ float red[4][8];
    int t = threadIdx.x;
    int m0 = blockIdx.x * 16;
    const size_t S = (size_t)NN * 256;
    if (t < 16) rs_s[t] = rsA[m0 + t] * (1.0f / 8192.0f);
    __syncthreads();
    int g = t >> 6, cq = (t & 63) * 4;
    float4 snv = *(const float4*)(sn + cq);
    float4 bv  = *(const float4*)(bias + cq);
#pragma unroll
    for (int r4 = 0; r4 < 4; ++r4) {
        int row = g * 4 + r4;
        size_t base = (size_t)(m0 + row) * 256 + cq;
        float4 a = {0.f, 0.f, 0.f, 0.f};
#pragma unroll
        for (int s = 0; s < 8; ++s) {
            float4 p = *(const float4*)(Cp + (size_t)s * S + base);
            a.x += p.x; a.y += p.y; a.z += p.z; a.w += p.w;
        }
        float rsv = rs_s[row];
        float4 o;
        o.x = fmaxf(a.x + bv.x - rsv * snv.x, 0.f);
        o.y = fmaxf(a.y + bv.y - rsv * snv.y, 0.f);
        o.z = fmaxf(a.z + bv.z - rsv * snv.z, 0.f);
        o.w = fmaxf(a.w + bv.w - rsv * snv.w, 0.f);
        *(float4*)&sh[row][cq] = o;
    }
    __syncthreads();
    int h = t & 127, rg = t >> 7;        // waves 0,1 -> rows 0..7; waves 2,3 -> rows 8..15
    float acc[8] = {};
    const float* wq = Wq1 + h;
    for (int n4 = 0; n4 < 64; ++n4) {
        int n = n4 * 4;
        float wa = wq[(size_t)(n + 0) * QH];
        float wb = wq[(size_t)(n + 1) * QH];
        float wcc = wq[(size_t)(n + 2) * QH];
        float wd = wq[(size_t)(n + 3) * QH];
#pragma unroll
        for (int r = 0; r < 8; ++r) {
            float4 sv = *(const float4*)&sh[rg * 8 + r][n];
            acc[r] = fmaf(sv.x, wa, fmaf(sv.y, wb, fmaf(sv.z, wcc, fmaf(sv.w, wd, acc[r]))));
        }
    }
    float b1v = bq1[h], w2v = Wq2[h];
    int wid = t >> 6, lane = t & 63;
#pragma unroll
    for (int r = 0; r < 8; ++r) {
        float v = fmaxf(acc[r] + b1v, 0.f) * w2v;
#pragma unroll
        for (int d = 32; d > 0; d >>= 1) v += __shfl_down(v, d, 64);
        if (lane == 0) red[wid][r] = v;
    }
    __syncthreads();
    if (t < 16) {
        int rg2 = t >> 3, r = t & 7;
        out[m0 + rg2 * 8 + r] = red[rg2 * 2][r] + red[rg2 * 2 + 1][r] + bq2[0];
    }
}

extern "C" void kernel_launch(void* const* d_in, const int* in_sizes, int n_in,
                              void* d_out, int out_size, void* d_ws, size_t ws_size,
                              hipStream_t stream) {
    const float* state = (const float*)d_in[0];
    const float* adj   = (const float*)d_in[1];
    const float* gamma = (const float*)d_in[2];
    const float* beta  = (const float*)d_in[3];
    const float* W1    = (const float*)d_in[4];
    const float* b1    = (const float*)d_in[5];
    const float* W2    = (const float*)d_in[6];
    const float* b2    = (const float*)d_in[7];
    const float* Wq1   = (const float*)d_in[8];
    const float* bq1   = (const float*)d_in[9];
    const float* Wq2   = (const float*)d_in[10];
    const float* bq2   = (const float*)d_in[11];
    float* out = (float*)d_out;

    char* ws = (char*)d_ws;
    float* psum  = (float*)(ws + 0);         // 128KB
    float* psq   = (float*)(ws + 131072);    // 128KB
    float* scale = (float*)(ws + 262144);
    float* shift = (float*)(ws + 262656);
    float* c1    = (float*)(ws + 263168);
    float* colA  = (float*)(ws + 264192);    // colsum(Y1q)  -- colA..s2 contiguous 4KB
    float* colB  = (float*)(ws + 265216);    // colsum(Y2q)
    float* colH1 = (float*)(ws + 266240);    // colsum(H1 fp32)
    float* s2    = (float*)(ws + 267264);
    unsigned short* W1st = (unsigned short*)(ws + 268288);   // [256][128] bf16
    unsigned short* W2t  = (unsigned short*)(ws + 333824);   // [256][256] bf16
    unsigned short* Ybuf = (unsigned short*)(ws + (size_t)1  * (1u << 20)); // [8192][256] bf16
    unsigned short* Ytb  = (unsigned short*)(ws + (size_t)5  * (1u << 20)); // [256][8192] bf16
    unsigned short* Hbuf = (unsigned short*)(ws + (size_t)9  * (1u << 20)); // [8192][256] bf16
    float*          rsA  = (float*)(ws + (size_t)14 * (1u << 20));          // [8192] fp32
    float*          Cp   = (float*)(ws + (size_t)22 * (1u << 20));          // [8][8192][256] fp32 (64MB)

    k_stats<<<256, 128, 0, stream>>>(state, psum, psq, colA, rsA);
    k_finalize<<<1, 256, 0, stream>>>(psum, psq, gamma, beta, W1, scale, shift, c1);
    k_prep_weights<<<384, 256, 0, stream>>>(W1, W2, scale, W1st, W2t);

    // Y1 = bn(state) @ W1  (= state @ (scale*W1) + c1); colsum(Y1_true) == 0 exactly
    k_small_gemm<256, 128, true, true><<<256, 256, 0, stream>>>(state, W1st, c1, Ybuf);
    k_transpose<<<dim3(128, 4), 256, 0, stream>>>(Ybuf, Ytb, colA);
    k_big_gemm3<true><<<dim3(64, 8), 256, 0, stream>>>(adj, Ytb, Cp, rsA);
    k_reduce8<<<512, 256, 0, stream>>>(Cp, rsA, b1, colA, Hbuf, colH1);   // H1 bf16 + colsum

    // Y2 = H1 @ W2; colsum(Y2_true) = colH1 @ W2 (fp32)
    k_small_gemm<256, 256, false, false><<<256, 256, 0, stream>>>(Hbuf, W2t, nullptr, Ybuf);
    k_transpose<<<dim3(128, 4), 256, 0, stream>>>(Ybuf, Ytb, colB);
    k_s2<<<1, 256, 0, stream>>>(colB, colH1, W2, s2);
    k_big_gemm3<false><<<dim3(64, 8), 256, 0, stream>>>(adj, Ytb, Cp, rsA);
    k_reduce_qhead<<<512, 256, 0, stream>>>(Cp, rsA, b2, s2, Wq1, bq1, Wq2, bq2, out);
}

// Round 2
// 638.568 us; speedup vs baseline: 1.0096x; 1.0096x over previous
//
#include <hip/hip_runtime.h>
#include <stdint.h>

#define NN 8192      // nodes
#define D0 128
#define D1 256
#define D2 256
#define QH 128
#define EPSV 1e-5f

using bf16x8 = __attribute__((ext_vector_type(8))) __bf16;
using f32x4  = __attribute__((ext_vector_type(4))) float;

__device__ __forceinline__ unsigned short f2bf(float f) {
    union { float f; unsigned int u; } v; v.f = f;
    unsigned int r = v.u + 0x7FFFu + ((v.u >> 16) & 1u);   // RNE
    return (unsigned short)(r >> 16);
}
__device__ __forceinline__ float bf2f(unsigned short h) {
    union { unsigned int u; float f; } v; v.u = ((unsigned int)h) << 16;
    return v.f;
}
// pack two fp32 -> one u32 of two bf16 (RNE), low = first arg
__device__ __forceinline__ unsigned pkbf(float a, float b) {
    unsigned r;
    asm("v_cvt_pk_bf16_f32 %0, %1, %2" : "=v"(r) : "v"(a), "v"(b));
    return r;
}
// async global->LDS, 16B per lane; lds dest is wave-uniform base (HW: base + lane*16)
__device__ __forceinline__ void async_ld16(const void* g, void* l) {
    __builtin_amdgcn_global_load_lds(
        (__attribute__((address_space(1))) void*)(g),
        (__attribute__((address_space(3))) void*)(l), 16, 0, 0);
}

// ---------------- batchnorm partial stats + zero the fp32 accumulators ----------------
__global__ void k_stats(const float* __restrict__ state,
                        float* __restrict__ psum, float* __restrict__ psq,
                        float* __restrict__ acc4k, float* __restrict__ rsA) {
    int j = threadIdx.x;            // 0..127 = feature
    int b = blockIdx.x;             // 0..255, 32 rows each
    int gid = b * 128 + j;
    if (gid < 8192) rsA[gid] = 0.f;          // row-sum accumulator (gemm1 atomics)
    if (gid < 1024) acc4k[gid] = 0.f;        // colA,colB,colH1,s2 (contiguous 4KB)
    const float* p = state + (size_t)b * 32 * D0 + j;
    float s = 0.f, sq = 0.f;
#pragma unroll 4
    for (int r = 0; r < 32; ++r) { float x = p[(size_t)r * D0]; s += x; sq += x * x; }
    psum[b * D0 + j] = s;
    psq [b * D0 + j] = sq;
}

// ---------------- finalize scale/shift + c1 ----------------
__global__ void k_finalize(const float* __restrict__ psum, const float* __restrict__ psq,
                           const float* __restrict__ gamma, const float* __restrict__ beta,
                           const float* __restrict__ W1,
                           float* __restrict__ scale, float* __restrict__ shift,
                           float* __restrict__ c1) {
    __shared__ float s_shift[D0];
    int t = threadIdx.x;            // 256 threads
    if (t < D0) {
        float s = 0.f, sq = 0.f;
        for (int b = 0; b < 256; ++b) { s += psum[b * D0 + t]; sq += psq[b * D0 + t]; }
        float mean = s * (1.0f / NN);
        float var  = sq * (1.0f / NN) - mean * mean;
        float sc = gamma[t] * rsqrtf(var + EPSV);
        float sh = beta[t] - mean * sc;
        scale[t] = sc; shift[t] = sh; s_shift[t] = sh;
    }
    __syncthreads();
    float acc = 0.f;
    for (int k = 0; k < D0; ++k) acc += s_shift[k] * W1[(size_t)k * D1 + t];
    c1[t] = acc;
}

// ---------------- weights -> bf16, transposed [n][k], W1 scaled ----------------
__global__ void k_prep_weights(const float* __restrict__ W1, const float* __restrict__ W2,
                               const float* __restrict__ scale,
                               unsigned short* __restrict__ W1st,  // [256][128]
                               unsigned short* __restrict__ W2t) { // [256][256]
    int idx = blockIdx.x * 256 + threadIdx.x;
    if (idx < 32768) {
        int n = idx >> 7, k = idx & 127;
        W1st[idx] = f2bf(W1[(size_t)k * D1 + n] * scale[k]);
    } else {
        int i = idx - 32768; int n = i >> 8, k = i & 255;
        W2t[i] = f2bf(W2[(size_t)k * D2 + n]);
    }
}

// ---------------- small MFMA GEMM: out[m][n] = A[m][k] @ Bt[n][k]^T (+ bias) ----------------
template <int N, int K, bool A_FP32, bool BIAS>
__global__ __launch_bounds__(256, 4) void k_small_gemm(
        const void* __restrict__ Aptr, const unsigned short* __restrict__ Bt,
        const float* __restrict__ bias, unsigned short* __restrict__ out) {
    constexpr int WN = N / 4;
    constexpr int NJ = WN / 16;
    constexpr int BI = N / 64;
    __shared__ unsigned short Alds[32 * 32];
    __shared__ unsigned short Blds[N * 32];
    int t = threadIdx.x, lane = t & 63, w = t >> 6;
    int m0 = blockIdx.x * 32;
    int lr = lane & 15, lk = (lane >> 4) * 8;
    int wc = w * WN;
    f32x4 acc[2][NJ] = {};

    for (int kk = 0; kk < K; kk += 32) {
        __syncthreads();
        if constexpr (A_FP32) {
            const float* A = (const float*)Aptr;
            int row = t >> 3, kc = (t & 7) * 4;
            float4 v = *(const float4*)(A + (size_t)(m0 + row) * K + kk + kc);
            uint2 p;
            p.x = ((unsigned)f2bf(v.y) << 16) | f2bf(v.x);
            p.y = ((unsigned)f2bf(v.w) << 16) | f2bf(v.z);
            *(uint2*)&Alds[row * 32 + kc] = p;
        } else {
            if (w < 2) {
                const unsigned short* A = (const unsigned short*)Aptr;
                int row = w * 16 + (lane >> 2);
                async_ld16(A + (size_t)(m0 + row) * K + kk + (lane & 3) * 8, &Alds[w * 512]);
            }
        }
#pragma unroll
        for (int i = 0; i < BI; ++i) {
            int n = w * WN + i * 16 + (lane >> 2);
            async_ld16(Bt + (size_t)n * K + kk + (lane & 3) * 8, &Blds[(w * WN + i * 16) * 32]);
        }
        __syncthreads();
        bf16x8 a[2], b[NJ];
#pragma unroll
        for (int i = 0; i < 2; ++i) a[i] = *(const bf16x8*)&Alds[(i * 16 + lr) * 32 + lk];
#pragma unroll
        for (int j = 0; j < NJ; ++j) b[j] = *(const bf16x8*)&Blds[(wc + j * 16 + lr) * 32 + lk];
#pragma unroll
        for (int i = 0; i < 2; ++i)
#pragma unroll
            for (int j = 0; j < NJ; ++j)
                acc[i][j] = __builtin_amdgcn_mfma_f32_16x16x32_bf16(a[i], b[j], acc[i][j], 0, 0, 0);
    }
    int q = lane >> 4;
#pragma unroll
    for (int j = 0; j < NJ; ++j) {
        int n = wc + j * 16 + lr;
        float bv = 0.f;
        if constexpr (BIAS) bv = bias[n];
#pragma unroll
        for (int i = 0; i < 2; ++i) {
#pragma unroll
            for (int r = 0; r < 4; ++r) {
                int m = m0 + i * 16 + q * 4 + r;
                out[(size_t)m * N + n] = f2bf(acc[i][j][r] + bv);
            }
        }
    }
}

// ---------------- transpose [8192][256] bf16 -> [256][8192] bf16, + fp32 colsum ----------------
__global__ void k_transpose(const unsigned short* __restrict__ in, unsigned short* __restrict__ out,
                            float* __restrict__ colsum) {
    __shared__ unsigned short tile[64 * 68];
    __shared__ float cp[4][64];
    int t = threadIdx.x;
    int r0 = blockIdx.x * 64, c0 = blockIdx.y * 64;
#pragma unroll
    for (int p = 0; p < 4; ++p) {
        int row = (t >> 4) + p * 16, col = (t & 15) * 4;
        *(ushort4*)&tile[row * 68 + col] = *(const ushort4*)&in[(size_t)(r0 + row) * 256 + c0 + col];
    }
    __syncthreads();
    int n = t >> 2;
#pragma unroll
    for (int s = 0; s < 2; ++s) {
        int mo = (t & 3) * 16 + s * 8;
        unsigned short v[8];
#pragma unroll
        for (int e = 0; e < 8; ++e) v[e] = tile[(mo + e) * 68 + n];
        *(uint4*)&out[(size_t)(c0 + n) * NN + r0 + mo] = *(const uint4*)v;
    }
    int col = t & 63, gg = t >> 6;
    float s = 0.f;
#pragma unroll
    for (int r = 0; r < 16; ++r) s += bf2f(tile[(gg * 16 + r) * 68 + col]);
    cp[gg][col] = s;
    __syncthreads();
    if (t < 64) atomicAdd(colsum + c0 + t, cp[0][t] + cp[1][t] + cp[2][t] + cp[3][t]);
}

// ---------------- big GEMM, fp32 A fused-cast, 8-wave / 64x64 wave tiles -------------
// Cp[ksplit] = f32A(cast bf16) @ Yt^T. BM=128, BN=256, BK=32, split-K=8. grid(64,8).
// 512 thr = 8 waves (2m x 4n), wave tile 64x64, acc[4][4] (64 VGPR) -> fits 128-VGPR cap,
// __launch_bounds__(512,4) => 2 blocks/CU = 16 waves/CU for cross-block latency hiding.
// A: reg-staged fp32 (2x float4/thread -> cvt_pk -> one swizzled ds_write_b128); rowsum fused.
// B: pre-swizzled-source global_load_lds. Double-buffered LDS (48KB), 1 barrier/K-step.
// Swizzle: 16B chunk c of row r stored at chunk c ^ xs(r), xs(r) = (r ^ (r>>2)) & 3.
template <bool RSUM>
__global__ __launch_bounds__(512, 4) void k_big_gemm4(
        const float* __restrict__ A, const unsigned short* __restrict__ Yt,
        float* __restrict__ Cp, float* __restrict__ rsA) {
    __shared__ unsigned short Alds[2][128 * 32];   // 8KB  x2
    __shared__ unsigned short Blds[2][256 * 32];   // 16KB x2 -> 48KB total
    int t = threadIdx.x, lane = t & 63, w = t >> 6;
    int m0 = blockIdx.x * 128;
    int kbeg = blockIdx.y * 1024;
    int wr = (w & 1) * 64, wc = (w >> 1) * 64;
    int lr = lane & 15, q = lane >> 4;
    f32x4 acc[4][4] = {};

    // A staging: thread covers (row = t>>2, seg = t&3 -> k [seg*8, seg*8+8))
    int arow = t >> 2, aseg = t & 3;
    int axs = (arow ^ (arow >> 2)) & 3;
    const float* agp = A + (size_t)(m0 + arow) * NN + kbeg + aseg * 8;
    int awr = arow * 32 + ((aseg ^ axs) & 3) * 8;          // shorts

    // B staging: wave w covers rows [w*32, w*32+32), 2 calls of 16 rows
    int srow = lane >> 2;
    int hsw = (lane & 3) ^ ((srow ^ (srow >> 2)) & 3);
    const unsigned short* bg0 = Yt + (size_t)(w * 32 + srow) * NN + kbeg + hsw * 8;
    const unsigned short* bg1 = Yt + (size_t)(w * 32 + 16 + srow) * NN + kbeg + hsw * 8;

    // read-side swizzle (shorts)
    int xsr = (lr ^ (lr >> 2)) & 3;
    int lks = ((q ^ xsr) & 3) * 8;

    float rs = 0.f;
    float4 av0, av1;

    // ---- prologue: stage tile 0 into buf 0
    av0 = *(const float4*)(agp + 0);
    av1 = *(const float4*)(agp + 4);
    async_ld16(bg0, &Blds[0][w * 1024]);
    async_ld16(bg1, &Blds[0][w * 1024 + 512]);
    {
        uint4 u = { pkbf(av0.x, av0.y), pkbf(av0.z, av0.w), pkbf(av1.x, av1.y), pkbf(av1.z, av1.w) };
        *(uint4*)&Alds[0][awr] = u;
    }
    if constexpr (RSUM)
        rs += av0.x + av0.y + av0.z + av0.w + av1.x + av1.y + av1.z + av1.w;
    __syncthreads();

#pragma unroll 2
    for (int it = 0; it < 32; ++it) {
        int p = it & 1;
        bool more = (it < 31);
        if (more) {
            int ko = (it + 1) * 32;
            av0 = *(const float4*)(agp + ko);            // in flight across MFMA below
            av1 = *(const float4*)(agp + ko + 4);
            async_ld16(bg0 + ko, &Blds[p ^ 1][w * 1024]);
            async_ld16(bg1 + ko, &Blds[p ^ 1][w * 1024 + 512]);
        }
        bf16x8 a[4];
#pragma unroll
        for (int i = 0; i < 4; ++i) a[i] = *(const bf16x8*)&Alds[p][(wr + i * 16 + lr) * 32 + lks];
#pragma unroll
        for (int j = 0; j < 4; ++j) {
            bf16x8 b = *(const bf16x8*)&Blds[p][(wc + j * 16 + lr) * 32 + lks];
#pragma unroll
            for (int i = 0; i < 4; ++i)
                acc[i][j] = __builtin_amdgcn_mfma_f32_16x16x32_bf16(a[i], b, acc[i][j], 0, 0, 0);
        }
        if (more) {
            uint4 u = { pkbf(av0.x, av0.y), pkbf(av0.z, av0.w), pkbf(av1.x, av1.y), pkbf(av1.z, av1.w) };
            *(uint4*)&Alds[p ^ 1][awr] = u;
            if constexpr (RSUM)
                rs += av0.x + av0.y + av0.z + av0.w + av1.x + av1.y + av1.z + av1.w;
        }
        __syncthreads();
    }

    float* outp = Cp + (size_t)blockIdx.y * NN * 256;
#pragma unroll
    for (int i = 0; i < 4; ++i)
#pragma unroll
        for (int j = 0; j < 4; ++j) {
            int n = wc + j * 16 + lr;
#pragma unroll
            for (int r = 0; r < 4; ++r) {
                int m = m0 + wr + i * 16 + q * 4 + r;
                outp[(size_t)m * 256 + n] = acc[i][j][r];
            }
        }
    if constexpr (RSUM) {
        rs += __shfl_xor(rs, 1, 64);
        rs += __shfl_xor(rs, 2, 64);
        if ((lane & 3) == 0) atomicAdd(rsA + m0 + arow, rs);
    }
}

// ---------------- s2[n] = colB[n] - sum_k colH1[k]*W2[k][n] ----------------
__global__ void k_s2(const float* __restrict__ colB, const float* __restrict__ colH1,
                     const float* __restrict__ W2, float* __restrict__ s2) {
    int n = threadIdx.x;
    float acc = 0.f;
    for (int k = 0; k < 256; ++k) acc += colH1[k] * W2[(size_t)k * 256 + n];
    s2[n] = colB[n] - acc;
}

// ---------------- reduce 8 split-K partials + bias + colsum-corr + relu -> bf16 H1 ----------
__global__ __launch_bounds__(256) void k_reduce8(
        const float* __restrict__ Cp, const float* __restrict__ rsA,
        const float* __restrict__ bias, const float* __restrict__ sn,
        unsigned short* __restrict__ out, float* __restrict__ colH1) {
    __shared__ float rs_s[16];
    __shared__ float cs[4][256];
    int t = threadIdx.x;
    int m0 = blockIdx.x * 16;
    const size_t S = (size_t)NN * 256;
    if (t < 16) rs_s[t] = rsA[m0 + t] * (1.0f / 8192.0f);
    __syncthreads();
    int g = t >> 6, cq = (t & 63) * 4;
    float4 snv = *(const float4*)(sn + cq);
    float4 bv  = *(const float4*)(bias + cq);
    float c0 = 0.f, c1a = 0.f, c2 = 0.f, c3 = 0.f;
#pragma unroll
    for (int r4 = 0; r4 < 4; ++r4) {
        int row = g * 4 + r4;
        size_t base = (size_t)(m0 + row) * 256 + cq;
        float4 a = {0.f, 0.f, 0.f, 0.f};
#pragma unroll
        for (int s = 0; s < 8; ++s) {
            float4 p = *(const float4*)(Cp + (size_t)s * S + base);
            a.x += p.x; a.y += p.y; a.z += p.z; a.w += p.w;
        }
        float rsv = rs_s[row];
        float x0 = fmaxf(a.x + bv.x - rsv * snv.x, 0.f);
        float x1 = fmaxf(a.y + bv.y - rsv * snv.y, 0.f);
        float x2 = fmaxf(a.z + bv.z - rsv * snv.z, 0.f);
        float x3 = fmaxf(a.w + bv.w - rsv * snv.w, 0.f);
        ushort4 o; o.x = f2bf(x0); o.y = f2bf(x1); o.z = f2bf(x2); o.w = f2bf(x3);
        *(ushort4*)(out + base) = o;
        c0 += x0; c1a += x1; c2 += x2; c3 += x3;
    }
    cs[g][cq] = c0; cs[g][cq + 1] = c1a; cs[g][cq + 2] = c2; cs[g][cq + 3] = c3;
    __syncthreads();
    float tot = cs[0][t] + cs[1][t] + cs[2][t] + cs[3][t];
    atomicAdd(colH1 + t, tot);
}

// ---------------- fused: reduce 8 partials -> H2(fp32, LDS only) -> Q-head -> out -------
__global__ __launch_bounds__(256) void k_reduce_qhead(
        const float* __restrict__ Cp, const float* __restrict__ rsA,
        const float* __restrict__ bias, const float* __restrict__ sn,
        const float* __restrict__ Wq1, const float* __restrict__ bq1,
        const float* __restrict__ Wq2, const float* __restrict__ bq2,
        float* __restrict__ out) {
    __shared__ float sh[16][256];   // 16KB
    __shared__ float rs_s[16];
    __shared__ float red[4][8];
    int t = threadIdx.x;
    int m0 = blockIdx.x * 16;
    const size_t S = (size_t)NN * 256;
    if (t < 16) rs_s[t] = rsA[m0 + t] * (1.0f / 8192.0f);
    __syncthreads();
    int g = t >> 6, cq = (t & 63) * 4;
    float4 snv = *(const float4*)(sn + cq);
    float4 bv  = *(const float4*)(bias + cq);
#pragma unroll
    for (int r4 = 0; r4 < 4; ++r4) {
        int row = g * 4 + r4;
        size_t base = (size_t)(m0 + row) * 256 + cq;
        float4 a = {0.f, 0.f, 0.f, 0.f};
#pragma unroll
        for (int s = 0; s < 8; ++s) {
            float4 p = *(const float4*)(Cp + (size_t)s * S + base);
            a.x += p.x; a.y += p.y; a.z += p.z; a.w += p.w;
        }
        float rsv = rs_s[row];
        float4 o;
        o.x = fmaxf(a.x + bv.x - rsv * snv.x, 0.f);
        o.y = fmaxf(a.y + bv.y - rsv * snv.y, 0.f);
        o.z = fmaxf(a.z + bv.z - rsv * snv.z, 0.f);
        o.w = fmaxf(a.w + bv.w - rsv * snv.w, 0.f);
        *(float4*)&sh[row][cq] = o;
    }
    __syncthreads();
    int h = t & 127, rg = t >> 7;        // waves 0,1 -> rows 0..7; waves 2,3 -> rows 8..15
    float acc[8] = {};
    const float* wq = Wq1 + h;
    for (int n4 = 0; n4 < 64; ++n4) {
        int n = n4 * 4;
        float wa = wq[(size_t)(n + 0) * QH];
        float wb = wq[(size_t)(n + 1) * QH];
        float wcc = wq[(size_t)(n + 2) * QH];
        float wd = wq[(size_t)(n + 3) * QH];
#pragma unroll
        for (int r = 0; r < 8; ++r) {
            float4 sv = *(const float4*)&sh[rg * 8 + r][n];
            acc[r] = fmaf(sv.x, wa, fmaf(sv.y, wb, fmaf(sv.z, wcc, fmaf(sv.w, wd, acc[r]))));
        }
    }
    float b1v = bq1[h], w2v = Wq2[h];
    int wid = t >> 6, lane = t & 63;
#pragma unroll
    for (int r = 0; r < 8; ++r) {
        float v = fmaxf(acc[r] + b1v, 0.f) * w2v;
#pragma unroll
        for (int d = 32; d > 0; d >>= 1) v += __shfl_down(v, d, 64);
        if (lane == 0) red[wid][r] = v;
    }
    __syncthreads();
    if (t < 16) {
        int rg2 = t >> 3, r = t & 7;
        out[m0 + rg2 * 8 + r] = red[rg2 * 2][r] + red[rg2 * 2 + 1][r] + bq2[0];
    }
}

extern "C" void kernel_launch(void* const* d_in, const int* in_sizes, int n_in,
                              void* d_out, int out_size, void* d_ws, size_t ws_size,
                              hipStream_t stream) {
    const float* state = (const float*)d_in[0];
    const float* adj   = (const float*)d_in[1];
    const float* gamma = (const float*)d_in[2];
    const float* beta  = (const float*)d_in[3];
    const float* W1    = (const float*)d_in[4];
    const float* b1    = (const float*)d_in[5];
    const float* W2    = (const float*)d_in[6];
    const float* b2    = (const float*)d_in[7];
    const float* Wq1   = (const float*)d_in[8];
    const float* bq1   = (const float*)d_in[9];
    const float* Wq2   = (const float*)d_in[10];
    const float* bq2   = (const float*)d_in[11];
    float* out = (float*)d_out;

    char* ws = (char*)d_ws;
    float* psum  = (float*)(ws + 0);         // 128KB
    float* psq   = (float*)(ws + 131072);    // 128KB
    float* scale = (float*)(ws + 262144);
    float* shift = (float*)(ws + 262656);
    float* c1    = (float*)(ws + 263168);
    float* colA  = (float*)(ws + 264192);    // colsum(Y1q)  -- colA..s2 contiguous 4KB
    float* colB  = (float*)(ws + 265216);    // colsum(Y2q)
    float* colH1 = (float*)(ws + 266240);    // colsum(H1 fp32)
    float* s2    = (float*)(ws + 267264);
    unsigned short* W1st = (unsigned short*)(ws + 268288);   // [256][128] bf16
    unsigned short* W2t  = (unsigned short*)(ws + 333824);   // [256][256] bf16
    unsigned short* Ybuf = (unsigned short*)(ws + (size_t)1  * (1u << 20)); // [8192][256] bf16
    unsigned short* Ytb  = (unsigned short*)(ws + (size_t)5  * (1u << 20)); // [256][8192] bf16
    unsigned short* Hbuf = (unsigned short*)(ws + (size_t)9  * (1u << 20)); // [8192][256] bf16
    float*          rsA  = (float*)(ws + (size_t)14 * (1u << 20));          // [8192] fp32
    float*          Cp   = (float*)(ws + (size_t)22 * (1u << 20));          // [8][8192][256] fp32 (64MB)

    k_stats<<<256, 128, 0, stream>>>(state, psum, psq, colA, rsA);
    k_finalize<<<1, 256, 0, stream>>>(psum, psq, gamma, beta, W1, scale, shift, c1);
    k_prep_weights<<<384, 256, 0, stream>>>(W1, W2, scale, W1st, W2t);

    // Y1 = bn(state) @ W1  (= state @ (scale*W1) + c1); colsum(Y1_true) == 0 exactly
    k_small_gemm<256, 128, true, true><<<256, 256, 0, stream>>>(state, W1st, c1, Ybuf);
    k_transpose<<<dim3(128, 4), 256, 0, stream>>>(Ybuf, Ytb, colA);
    k_big_gemm4<true><<<dim3(64, 8), 512, 0, stream>>>(adj, Ytb, Cp, rsA);
    k_reduce8<<<512, 256, 0, stream>>>(Cp, rsA, b1, colA, Hbuf, colH1);   // H1 bf16 + colsum

    // Y2 = H1 @ W2; colsum(Y2_true) = colH1 @ W2 (fp32)
    k_small_gemm<256, 256, false, false><<<256, 256, 0, stream>>>(Hbuf, W2t, nullptr, Ybuf);
    k_transpose<<<dim3(128, 4), 256, 0, stream>>>(Ybuf, Ytb, colB);
    k_s2<<<1, 256, 0, stream>>>(colB, colH1, W2, s2);
    k_big_gemm4<false><<<dim3(64, 8), 512, 0, stream>>>(adj, Ytb, Cp, rsA);
    k_reduce_qhead<<<512, 256, 0, stream>>>(Cp, rsA, b2, s2, Wq1, bq1, Wq2, bq2, out);
}

// Round 3
// 599.078 us; speedup vs baseline: 1.0761x; 1.0659x over previous
//
#include <hip/hip_runtime.h>
#include <stdint.h>

#define NN 8192      // nodes
#define D0 128
#define D1 256
#define D2 256
#define QH 128
#define EPSV 1e-5f

using bf16x8 = __attribute__((ext_vector_type(8))) __bf16;
using f32x4  = __attribute__((ext_vector_type(4))) float;

__device__ __forceinline__ unsigned short f2bf(float f) {
    union { float f; unsigned int u; } v; v.f = f;
    unsigned int r = v.u + 0x7FFFu + ((v.u >> 16) & 1u);   // RNE
    return (unsigned short)(r >> 16);
}
__device__ __forceinline__ float bf2f(unsigned short h) {
    union { unsigned int u; float f; } v; v.u = ((unsigned int)h) << 16;
    return v.f;
}
// async global->LDS, 16B per lane; lds dest is wave-uniform base (HW: base + lane*16)
__device__ __forceinline__ void async_ld16(const void* g, void* l) {
    __builtin_amdgcn_global_load_lds(
        (__attribute__((address_space(1))) void*)(g),
        (__attribute__((address_space(3))) void*)(l), 16, 0, 0);
}

// ---------------- cast A fp32 -> bf16 (row-major) + fp32 rowsums ----------------
// one block per row; 256 threads x 32 elements. Leaves Abf L3-resident for both gemms.
__global__ __launch_bounds__(256) void k_castA(const float* __restrict__ A,
                                               unsigned short* __restrict__ Abf,
                                               float* __restrict__ rs) {
    __shared__ float sred[256];
    int t = threadIdx.x;
    size_t row = blockIdx.x;
    const float* ap = A + row * NN;
    unsigned short* op = Abf + row * NN;
    float s = 0.f;
#pragma unroll
    for (int i = 0; i < 8; ++i) {
        int c = i * 1024 + t * 4;
        float4 v = *(const float4*)(ap + c);
        s += v.x + v.y + v.z + v.w;
        ushort4 o; o.x = f2bf(v.x); o.y = f2bf(v.y); o.z = f2bf(v.z); o.w = f2bf(v.w);
        *(ushort4*)(op + c) = o;
    }
    sred[t] = s;
    __syncthreads();
    if (t < 128) sred[t] += sred[t + 128];
    __syncthreads();
    if (t < 64) {
        float v = sred[t] + sred[t + 64];
#pragma unroll
        for (int d = 32; d > 0; d >>= 1) v += __shfl_down(v, d, 64);
        if (t == 0) rs[row] = v;
    }
}

// ---------------- batchnorm partial stats + zero the small fp32 accumulators ----------------
__global__ void k_stats(const float* __restrict__ state,
                        float* __restrict__ psum, float* __restrict__ psq,
                        float* __restrict__ acc4k) {
    int j = threadIdx.x;            // 0..127 = feature
    int b = blockIdx.x;             // 0..255, 32 rows each
    int gid = b * 128 + j;
    if (gid < 1024) acc4k[gid] = 0.f;        // colA,colB,colH1,s2 (contiguous 4KB)
    const float* p = state + (size_t)b * 32 * D0 + j;
    float s = 0.f, sq = 0.f;
#pragma unroll 4
    for (int r = 0; r < 32; ++r) { float x = p[(size_t)r * D0]; s += x; sq += x * x; }
    psum[b * D0 + j] = s;
    psq [b * D0 + j] = sq;
}

// ---------------- finalize scale/shift + c1 ----------------
__global__ void k_finalize(const float* __restrict__ psum, const float* __restrict__ psq,
                           const float* __restrict__ gamma, const float* __restrict__ beta,
                           const float* __restrict__ W1,
                           float* __restrict__ scale, float* __restrict__ shift,
                           float* __restrict__ c1) {
    __shared__ float s_shift[D0];
    int t = threadIdx.x;            // 256 threads
    if (t < D0) {
        float s = 0.f, sq = 0.f;
        for (int b = 0; b < 256; ++b) { s += psum[b * D0 + t]; sq += psq[b * D0 + t]; }
        float mean = s * (1.0f / NN);
        float var  = sq * (1.0f / NN) - mean * mean;
        float sc = gamma[t] * rsqrtf(var + EPSV);
        float sh = beta[t] - mean * sc;
        scale[t] = sc; shift[t] = sh; s_shift[t] = sh;
    }
    __syncthreads();
    float acc = 0.f;
    for (int k = 0; k < D0; ++k) acc += s_shift[k] * W1[(size_t)k * D1 + t];
    c1[t] = acc;
}

// ---------------- weights -> bf16, transposed [n][k], W1 scaled ----------------
__global__ void k_prep_weights(const float* __restrict__ W1, const float* __restrict__ W2,
                               const float* __restrict__ scale,
                               unsigned short* __restrict__ W1st,  // [256][128]
                               unsigned short* __restrict__ W2t) { // [256][256]
    int idx = blockIdx.x * 256 + threadIdx.x;
    if (idx < 32768) {
        int n = idx >> 7, k = idx & 127;
        W1st[idx] = f2bf(W1[(size_t)k * D1 + n] * scale[k]);
    } else {
        int i = idx - 32768; int n = i >> 8, k = i & 255;
        W2t[i] = f2bf(W2[(size_t)k * D2 + n]);
    }
}

// ---------------- small MFMA GEMM: out[m][n] = A[m][k] @ Bt[n][k]^T (+ bias) ----------------
template <int N, int K, bool A_FP32, bool BIAS>
__global__ __launch_bounds__(256, 4) void k_small_gemm(
        const void* __restrict__ Aptr, const unsigned short* __restrict__ Bt,
        const float* __restrict__ bias, unsigned short* __restrict__ out) {
    constexpr int WN = N / 4;
    constexpr int NJ = WN / 16;
    constexpr int BI = N / 64;
    __shared__ unsigned short Alds[32 * 32];
    __shared__ unsigned short Blds[N * 32];
    int t = threadIdx.x, lane = t & 63, w = t >> 6;
    int m0 = blockIdx.x * 32;
    int lr = lane & 15, lk = (lane >> 4) * 8;
    int wc = w * WN;
    f32x4 acc[2][NJ] = {};

    for (int kk = 0; kk < K; kk += 32) {
        __syncthreads();
        if constexpr (A_FP32) {
            const float* A = (const float*)Aptr;
            int row = t >> 3, kc = (t & 7) * 4;
            float4 v = *(const float4*)(A + (size_t)(m0 + row) * K + kk + kc);
            uint2 p;
            p.x = ((unsigned)f2bf(v.y) << 16) | f2bf(v.x);
            p.y = ((unsigned)f2bf(v.w) << 16) | f2bf(v.z);
            *(uint2*)&Alds[row * 32 + kc] = p;
        } else {
            if (w < 2) {
                const unsigned short* A = (const unsigned short*)Aptr;
                int row = w * 16 + (lane >> 2);
                async_ld16(A + (size_t)(m0 + row) * K + kk + (lane & 3) * 8, &Alds[w * 512]);
            }
        }
#pragma unroll
        for (int i = 0; i < BI; ++i) {
            int n = w * WN + i * 16 + (lane >> 2);
            async_ld16(Bt + (size_t)n * K + kk + (lane & 3) * 8, &Blds[(w * WN + i * 16) * 32]);
        }
        __syncthreads();
        bf16x8 a[2], b[NJ];
#pragma unroll
        for (int i = 0; i < 2; ++i) a[i] = *(const bf16x8*)&Alds[(i * 16 + lr) * 32 + lk];
#pragma unroll
        for (int j = 0; j < NJ; ++j) b[j] = *(const bf16x8*)&Blds[(wc + j * 16 + lr) * 32 + lk];
#pragma unroll
        for (int i = 0; i < 2; ++i)
#pragma unroll
            for (int j = 0; j < NJ; ++j)
                acc[i][j] = __builtin_amdgcn_mfma_f32_16x16x32_bf16(a[i], b[j], acc[i][j], 0, 0, 0);
    }
    int q = lane >> 4;
#pragma unroll
    for (int j = 0; j < NJ; ++j) {
        int n = wc + j * 16 + lr;
        float bv = 0.f;
        if constexpr (BIAS) bv = bias[n];
#pragma unroll
        for (int i = 0; i < 2; ++i) {
#pragma unroll
            for (int r = 0; r < 4; ++r) {
                int m = m0 + i * 16 + q * 4 + r;
                out[(size_t)m * N + n] = f2bf(acc[i][j][r] + bv);
            }
        }
    }
}

// ---------------- transpose [8192][256] bf16 -> [256][8192] bf16, + fp32 colsum ----------------
__global__ void k_transpose(const unsigned short* __restrict__ in, unsigned short* __restrict__ out,
                            float* __restrict__ colsum) {
    __shared__ unsigned short tile[64 * 68];
    __shared__ float cp[4][64];
    int t = threadIdx.x;
    int r0 = blockIdx.x * 64, c0 = blockIdx.y * 64;
#pragma unroll
    for (int p = 0; p < 4; ++p) {
        int row = (t >> 4) + p * 16, col = (t & 15) * 4;
        *(ushort4*)&tile[row * 68 + col] = *(const ushort4*)&in[(size_t)(r0 + row) * 256 + c0 + col];
    }
    __syncthreads();
    int n = t >> 2;
#pragma unroll
    for (int s = 0; s < 2; ++s) {
        int mo = (t & 3) * 16 + s * 8;
        unsigned short v[8];
#pragma unroll
        for (int e = 0; e < 8; ++e) v[e] = tile[(mo + e) * 68 + n];
        *(uint4*)&out[(size_t)(c0 + n) * NN + r0 + mo] = *(const uint4*)v;
    }
    int col = t & 63, gg = t >> 6;
    float s = 0.f;
#pragma unroll
    for (int r = 0; r < 16; ++r) s += bf2f(tile[(gg * 16 + r) * 68 + col]);
    cp[gg][col] = s;
    __syncthreads();
    if (t < 64) atomicAdd(colsum + c0 + t, cp[0][t] + cp[1][t] + cp[2][t] + cp[3][t]);
}

// ---------------- big GEMM: bf16 A, depth-2 counted-vmcnt pipeline -------------
// Cp[ksplit] = Abf @ Yt^T. BM=128, BN=256, BK=32, split-K=8. grid(64,8).
// 512 thr = 8 waves (2m x 4n), wave tile 64x64, acc[4][4]. 3 LDS buffers (72KB),
// prefetch 2 tiles ahead; per K-step: issue 3 asyncs (tile it+2), ds_read+MFMA (tile it),
// s_waitcnt vmcnt(3) [tile it+1 landed, it+2's 3 stay in flight] + raw s_barrier.
// Never drains vmcnt to 0 in the main loop (T3/T4). Swizzle identical to prior rounds.
__global__ __launch_bounds__(512, 4) void k_big_gemm5(
        const unsigned short* __restrict__ Abf, const unsigned short* __restrict__ Yt,
        float* __restrict__ Cp) {
    __shared__ unsigned short Alds[3][128 * 32];   // 8KB  x3
    __shared__ unsigned short Blds[3][256 * 32];   // 16KB x3 -> 72KB total
    int t = threadIdx.x, lane = t & 63, w = t >> 6;
    int m0 = blockIdx.x * 128;
    int kbeg = blockIdx.y * 1024;
    int wr = (w & 1) * 64, wc = (w >> 1) * 64;
    int lr = lane & 15, q = lane >> 4;
    f32x4 acc[4][4] = {};

    // staging addresses (swizzled k-chunk per lane)
    int srow = lane >> 2;                              // 0..15 within 16-row group
    int hsw = (lane & 3) ^ ((srow ^ (srow >> 2)) & 3); // k-chunk this lane fetches
    const unsigned short* agp = Abf + (size_t)(m0 + w * 16 + srow) * NN + kbeg + hsw * 8;
    const unsigned short* bg0 = Yt + (size_t)(w * 32 + srow) * NN + kbeg + hsw * 8;
    const unsigned short* bg1 = Yt + (size_t)(w * 32 + 16 + srow) * NN + kbeg + hsw * 8;
    unsigned short* aL  = (unsigned short*)Alds + w * 512;   // wave-uniform LDS bases
    unsigned short* bL0 = (unsigned short*)Blds + w * 1024;
    unsigned short* bL1 = bL0 + 512;
    // read-side swizzle (shorts)
    int xsr = (lr ^ (lr >> 2)) & 3;
    int lks = ((q ^ xsr) & 3) * 8;

    // ---- prologue: stage tiles 0 and 1 into buffers 0 and 1
#pragma unroll
    for (int pt = 0; pt < 2; ++pt) {
        async_ld16(agp + pt * 32, aL  + pt * 4096);
        async_ld16(bg0 + pt * 32, bL0 + pt * 8192);
        async_ld16(bg1 + pt * 32, bL1 + pt * 8192);
    }
    asm volatile("s_waitcnt vmcnt(3)" ::: "memory");   // tile 0 landed
    __builtin_amdgcn_s_barrier();
    __builtin_amdgcn_sched_barrier(0);

    int cur = 0;
#define GEMM5_COMPUTE(BUF)                                                              \
    {                                                                                   \
        const unsigned short* Ab = (const unsigned short*)Alds + (BUF) * 4096;          \
        const unsigned short* Bb = (const unsigned short*)Blds + (BUF) * 8192;          \
        bf16x8 a[4];                                                                    \
        _Pragma("unroll")                                                               \
        for (int i = 0; i < 4; ++i) a[i] = *(const bf16x8*)&Ab[(wr + i * 16 + lr) * 32 + lks]; \
        _Pragma("unroll")                                                               \
        for (int j = 0; j < 4; ++j) {                                                   \
            bf16x8 b = *(const bf16x8*)&Bb[(wc + j * 16 + lr) * 32 + lks];              \
            _Pragma("unroll")                                                           \
            for (int i = 0; i < 4; ++i)                                                 \
                acc[i][j] = __builtin_amdgcn_mfma_f32_16x16x32_bf16(a[i], b, acc[i][j], 0, 0, 0); \
        }                                                                               \
    }

#pragma unroll 3
    for (int it = 0; it < 30; ++it) {
        int nb = cur + 2; if (nb >= 3) nb -= 3;        // buffer for tile it+2
        int ko = (it + 2) * 32;
        async_ld16(agp + ko, aL  + nb * 4096);
        async_ld16(bg0 + ko, bL0 + nb * 8192);
        async_ld16(bg1 + ko, bL1 + nb * 8192);
        GEMM5_COMPUTE(cur)
        asm volatile("s_waitcnt vmcnt(3)" ::: "memory");   // tile it+1 landed
        __builtin_amdgcn_s_barrier();
        __builtin_amdgcn_sched_barrier(0);
        ++cur; if (cur >= 3) cur = 0;
    }
    // it = 30: no prefetch; drain tile 31's loads
    GEMM5_COMPUTE(cur)
    asm volatile("s_waitcnt vmcnt(0)" ::: "memory");
    __builtin_amdgcn_s_barrier();
    __builtin_amdgcn_sched_barrier(0);
    ++cur; if (cur >= 3) cur = 0;
    // it = 31: last tile, no barrier needed after
    GEMM5_COMPUTE(cur)
#undef GEMM5_COMPUTE

    float* outp = Cp + (size_t)blockIdx.y * NN * 256;
#pragma unroll
    for (int i = 0; i < 4; ++i)
#pragma unroll
        for (int j = 0; j < 4; ++j) {
            int n = wc + j * 16 + lr;
#pragma unroll
            for (int r = 0; r < 4; ++r) {
                int m = m0 + wr + i * 16 + q * 4 + r;
                outp[(size_t)m * 256 + n] = acc[i][j][r];
            }
        }
}

// ---------------- s2[n] = colB[n] - sum_k colH1[k]*W2[k][n] ----------------
__global__ void k_s2(const float* __restrict__ colB, const float* __restrict__ colH1,
                     const float* __restrict__ W2, float* __restrict__ s2) {
    int n = threadIdx.x;
    float acc = 0.f;
    for (int k = 0; k < 256; ++k) acc += colH1[k] * W2[(size_t)k * 256 + n];
    s2[n] = colB[n] - acc;
}

// ---------------- reduce 8 split-K partials + bias + colsum-corr + relu -> bf16 H1 ----------
__global__ __launch_bounds__(256) void k_reduce8(
        const float* __restrict__ Cp, const float* __restrict__ rsA,
        const float* __restrict__ bias, const float* __restrict__ sn,
        unsigned short* __restrict__ out, float* __restrict__ colH1) {
    __shared__ float rs_s[16];
    __shared__ float cs[4][256];
    int t = threadIdx.x;
    int m0 = blockIdx.x * 16;
    const size_t S = (size_t)NN * 256;
    if (t < 16) rs_s[t] = rsA[m0 + t] * (1.0f / 8192.0f);
    __syncthreads();
    int g = t >> 6, cq = (t & 63) * 4;
    float4 snv = *(const float4*)(sn + cq);
    float4 bv  = *(const float4*)(bias + cq);
    float c0 = 0.f, c1a = 0.f, c2 = 0.f, c3 = 0.f;
#pragma unroll
    for (int r4 = 0; r4 < 4; ++r4) {
        int row = g * 4 + r4;
        size_t base = (size_t)(m0 + row) * 256 + cq;
        float4 a = {0.f, 0.f, 0.f, 0.f};
#pragma unroll
        for (int s = 0; s < 8; ++s) {
            float4 p = *(const float4*)(Cp + (size_t)s * S + base);
            a.x += p.x; a.y += p.y; a.z += p.z; a.w += p.w;
        }
        float rsv = rs_s[row];
        float x0 = fmaxf(a.x + bv.x - rsv * snv.x, 0.f);
        float x1 = fmaxf(a.y + bv.y - rsv * snv.y, 0.f);
        float x2 = fmaxf(a.z + bv.z - rsv * snv.z, 0.f);
        float x3 = fmaxf(a.w + bv.w - rsv * snv.w, 0.f);
        ushort4 o; o.x = f2bf(x0); o.y = f2bf(x1); o.z = f2bf(x2); o.w = f2bf(x3);
        *(ushort4*)(out + base) = o;
        c0 += x0; c1a += x1; c2 += x2; c3 += x3;
    }
    cs[g][cq] = c0; cs[g][cq + 1] = c1a; cs[g][cq + 2] = c2; cs[g][cq + 3] = c3;
    __syncthreads();
    float tot = cs[0][t] + cs[1][t] + cs[2][t] + cs[3][t];
    atomicAdd(colH1 + t, tot);
}

// ---------------- fused: reduce 8 partials -> H2(fp32, LDS only) -> Q-head -> out -------
__global__ __launch_bounds__(256) void k_reduce_qhead(
        const float* __restrict__ Cp, const float* __restrict__ rsA,
        const float* __restrict__ bias, const float* __restrict__ sn,
        const float* __restrict__ Wq1, const float* __restrict__ bq1,
        const float* __restrict__ Wq2, const float* __restrict__ bq2,
        float* __restrict__ out) {
    __shared__ float sh[16][256];   // 16KB
    __shared__ float rs_s[16];
    __shared__ float red[4][8];
    int t = threadIdx.x;
    int m0 = blockIdx.x * 16;
    const size_t S = (size_t)NN * 256;
    if (t < 16) rs_s[t] = rsA[m0 + t] * (1.0f / 8192.0f);
    __syncthreads();
    int g = t >> 6, cq = (t & 63) * 4;
    float4 snv = *(const float4*)(sn + cq);
    float4 bv  = *(const float4*)(bias + cq);
#pragma unroll
    for (int r4 = 0; r4 < 4; ++r4) {
        int row = g * 4 + r4;
        size_t base = (size_t)(m0 + row) * 256 + cq;
        float4 a = {0.f, 0.f, 0.f, 0.f};
#pragma unroll
        for (int s = 0; s < 8; ++s) {
            float4 p = *(const float4*)(Cp + (size_t)s * S + base);
            a.x += p.x; a.y += p.y; a.z += p.z; a.w += p.w;
        }
        float rsv = rs_s[row];
        float4 o;
        o.x = fmaxf(a.x + bv.x - rsv * snv.x, 0.f);
        o.y = fmaxf(a.y + bv.y - rsv * snv.y, 0.f);
        o.z = fmaxf(a.z + bv.z - rsv * snv.z, 0.f);
        o.w = fmaxf(a.w + bv.w - rsv * snv.w, 0.f);
        *(float4*)&sh[row][cq] = o;
    }
    __syncthreads();
    int h = t & 127, rg = t >> 7;        // waves 0,1 -> rows 0..7; waves 2,3 -> rows 8..15
    float acc[8] = {};
    const float* wq = Wq1 + h;
    for (int n4 = 0; n4 < 64; ++n4) {
        int n = n4 * 4;
        float wa = wq[(size_t)(n + 0) * QH];
        float wb = wq[(size_t)(n + 1) * QH];
        float wcc = wq[(size_t)(n + 2) * QH];
        float wd = wq[(size_t)(n + 3) * QH];
#pragma unroll
        for (int r = 0; r < 8; ++r) {
            float4 sv = *(const float4*)&sh[rg * 8 + r][n];
            acc[r] = fmaf(sv.x, wa, fmaf(sv.y, wb, fmaf(sv.z, wcc, fmaf(sv.w, wd, acc[r]))));
        }
    }
    float b1v = bq1[h], w2v = Wq2[h];
    int wid = t >> 6, lane = t & 63;
#pragma unroll
    for (int r = 0; r < 8; ++r) {
        float v = fmaxf(acc[r] + b1v, 0.f) * w2v;
#pragma unroll
        for (int d = 32; d > 0; d >>= 1) v += __shfl_down(v, d, 64);
        if (lane == 0) red[wid][r] = v;
    }
    __syncthreads();
    if (t < 16) {
        int rg2 = t >> 3, r = t & 7;
        out[m0 + rg2 * 8 + r] = red[rg2 * 2][r] + red[rg2 * 2 + 1][r] + bq2[0];
    }
}

extern "C" void kernel_launch(void* const* d_in, const int* in_sizes, int n_in,
                              void* d_out, int out_size, void* d_ws, size_t ws_size,
                              hipStream_t stream) {
    const float* state = (const float*)d_in[0];
    const float* adj   = (const float*)d_in[1];
    const float* gamma = (const float*)d_in[2];
    const float* beta  = (const float*)d_in[3];
    const float* W1    = (const float*)d_in[4];
    const float* b1    = (const float*)d_in[5];
    const float* W2    = (const float*)d_in[6];
    const float* b2    = (const float*)d_in[7];
    const float* Wq1   = (const float*)d_in[8];
    const float* bq1   = (const float*)d_in[9];
    const float* Wq2   = (const float*)d_in[10];
    const float* bq2   = (const float*)d_in[11];
    float* out = (float*)d_out;

    char* ws = (char*)d_ws;
    float* psum  = (float*)(ws + 0);         // 128KB
    float* psq   = (float*)(ws + 131072);    // 128KB
    float* scale = (float*)(ws + 262144);
    float* shift = (float*)(ws + 262656);
    float* c1    = (float*)(ws + 263168);
    float* colA  = (float*)(ws + 264192);    // colsum(Y1q)  -- colA..s2 contiguous 4KB
    float* colB  = (float*)(ws + 265216);    // colsum(Y2q)
    float* colH1 = (float*)(ws + 266240);    // colsum(H1 fp32)
    float* s2    = (float*)(ws + 267264);
    unsigned short* W1st = (unsigned short*)(ws + 268288);   // [256][128] bf16
    unsigned short* W2t  = (unsigned short*)(ws + 333824);   // [256][256] bf16
    unsigned short* Ybuf = (unsigned short*)(ws + (size_t)1  * (1u << 20)); // [8192][256] bf16
    unsigned short* Ytb  = (unsigned short*)(ws + (size_t)5  * (1u << 20)); // [256][8192] bf16
    unsigned short* Hbuf = (unsigned short*)(ws + (size_t)9  * (1u << 20)); // [8192][256] bf16
    float*          rsA  = (float*)(ws + (size_t)14 * (1u << 20));          // [8192] fp32
    float*          Cp   = (float*)(ws + (size_t)22 * (1u << 20));          // [8][8192][256] fp32 (64MB)
    unsigned short* Abf  = (unsigned short*)(ws + (size_t)128 * (1u << 20)); // [8192][8192] bf16 (134MB)

    k_castA<<<8192, 256, 0, stream>>>(adj, Abf, rsA);
    k_stats<<<256, 128, 0, stream>>>(state, psum, psq, colA);
    k_finalize<<<1, 256, 0, stream>>>(psum, psq, gamma, beta, W1, scale, shift, c1);
    k_prep_weights<<<384, 256, 0, stream>>>(W1, W2, scale, W1st, W2t);

    // Y1 = bn(state) @ W1  (= state @ (scale*W1) + c1); colsum(Y1_true) == 0 exactly
    k_small_gemm<256, 128, true, true><<<256, 256, 0, stream>>>(state, W1st, c1, Ybuf);
    k_transpose<<<dim3(128, 4), 256, 0, stream>>>(Ybuf, Ytb, colA);
    k_big_gemm5<<<dim3(64, 8), 512, 0, stream>>>(Abf, Ytb, Cp);
    k_reduce8<<<512, 256, 0, stream>>>(Cp, rsA, b1, colA, Hbuf, colH1);   // H1 bf16 + colsum

    // Y2 = H1 @ W2; colsum(Y2_true) = colH1 @ W2 (fp32)
    k_small_gemm<256, 256, false, false><<<256, 256, 0, stream>>>(Hbuf, W2t, nullptr, Ybuf);
    k_transpose<<<dim3(128, 4), 256, 0, stream>>>(Ybuf, Ytb, colB);
    k_s2<<<1, 256, 0, stream>>>(colB, colH1, W2, s2);
    k_big_gemm5<<<dim3(64, 8), 512, 0, stream>>>(Abf, Ytb, Cp);
    k_reduce_qhead<<<512, 256, 0, stream>>>(Cp, rsA, b2, s2, Wq1, bq1, Wq2, bq2, out);
}